// Round 5
// baseline (135.735 us; speedup 1.0000x reference)
//
#include <hip/hip_runtime.h>
#include <hip/hip_bf16.h>

// NT-Xent loss, BS=4096, D=256, TAU=0.5.
// R5 = R4 with compile fix: nontemporal stores via clang ext-vector f32x4
// (HIP float4 is a class type -> rejected by __builtin_nontemporal_store).
// fp8-e4m3 Gram inputs (halve L2 working set + read volume), nontemporal
// P stores, launch_bounds(256,2) on kgemm, LDS-staged coalesced knorm.
//
// znsw layout (fragment-native for mfma_f32_16x16x32_fp8_fp8):
//   16-row group rg, chunk-pair kbp (0..3): 64 lanes x 16B at
//   byte ((rg*4+kbp)*64 + fl)*16. Lane fl: row = rg*16 + (fl&15),
//   low 8B  = k = (2*kbp+0)*32 + (fl>>4)*8 + j  (j=0..7),
//   high 8B = k = (2*kbp+1)*32 + (fl>>4)*8 + j.

#define N_ROWS 8192
#define BSZ    4096
#define DIM    256
#define INV_TAU 2.0f
#define EPS_REF 1e-8f
#define COS_EPS 1e-8f
#define NG      128                    // 64-row groups
#define NTT     (NG * (NG + 1) / 2)    // 8256 triangular wave-tiles
#define NBLK    (NTT / 4)              // 2064 blocks of 4 waves

typedef __attribute__((ext_vector_type(4))) float f32x4;
typedef long long i64;
typedef union { int4 v; i64 d[2]; } pack16;

// ---------------- Kernel 1: normalize + fp8 quantize + fragment swizzle -----
// One block per 16-row group; all global accesses coalesced 16B/lane.
__global__ __launch_bounds__(256) void knorm(const float* __restrict__ zi,
                                             const float* __restrict__ zj,
                                             unsigned char* __restrict__ znsw) {
    __shared__ float lds[4096];    // 16 rows x 256
    __shared__ float nrm[16];
    const int rg = blockIdx.x;     // 0..511
    const int t  = threadIdx.x;
    const int row0 = rg * 16;

    #pragma unroll
    for (int s = 0; s < 4; ++s) {
        const int e = s * 1024 + t * 4;          // element in 16x256 panel
        const int r = row0 + (e >> 8);
        const int k = e & 255;
        const float* src = (r < BSZ) ? zi + (size_t)r * DIM + k
                                     : zj + (size_t)(r - BSZ) * DIM + k;
        *(float4*)&lds[e] = *(const float4*)src;
    }
    __syncthreads();

    {   // norms: 16 threads per row, 16 elems each, xor-reduce within wave
        const int r = t >> 4, p = t & 15;
        float ss = 0.f;
        #pragma unroll
        for (int j = 0; j < 16; ++j) { const float x = lds[r * 256 + p * 16 + j]; ss += x * x; }
        ss += __shfl_xor(ss, 1); ss += __shfl_xor(ss, 2);
        ss += __shfl_xor(ss, 4); ss += __shfl_xor(ss, 8);
        if (p == 0) nrm[r] = 1.0f / fmaxf(sqrtf(ss), COS_EPS);
    }
    __syncthreads();

    // emit one 16B fragment word per thread (block writes 4KB contiguous)
    const int kbp = t >> 6, fl = t & 63;
    const int r16 = fl & 15, q = fl >> 4;
    const float inv = nrm[r16];
    int w[4];
    #pragma unroll
    for (int h = 0; h < 2; ++h) {
        const int kk = (2 * kbp + h) * 32 + q * 8;
        float f[8];
        #pragma unroll
        for (int j = 0; j < 8; ++j) f[j] = lds[r16 * 256 + kk + j] * inv;
        int a = 0, b = 0;
        a = __builtin_amdgcn_cvt_pk_fp8_f32(f[0], f[1], a, false);
        a = __builtin_amdgcn_cvt_pk_fp8_f32(f[2], f[3], a, true);
        b = __builtin_amdgcn_cvt_pk_fp8_f32(f[4], f[5], b, false);
        b = __builtin_amdgcn_cvt_pk_fp8_f32(f[6], f[7], b, true);
        w[h * 2] = a; w[h * 2 + 1] = b;
    }
    *(int4*)(znsw + ((size_t)(rg * 4 + kbp) * 64 + fl) * 16) = make_int4(w[0], w[1], w[2], w[3]);
}

// ---------------- Kernel 2: triangular Gram, direct-load fp8 MFMA -----------
__global__ __launch_bounds__(256, 2) void kgemm(const unsigned char* __restrict__ znsw,
                                                float* __restrict__ P,
                                                float* __restrict__ selfdot,
                                                float* __restrict__ pairdot) {
    const int w = threadIdx.x >> 6;
    const int l = threadIdx.x & 63;
    const int t = blockIdx.x * 4 + w;

    // triangular decode: S(g) = g*(257-g)/2 <= t < S(g+1)
    int gi = (int)((257.0f - sqrtf(66049.0f - 8.0f * (float)t)) * 0.5f);
    while ((gi + 1) * (257 - (gi + 1)) / 2 <= t) ++gi;
    while (gi * (257 - gi) / 2 > t) --gi;
    const int gj = gi + (t - gi * (257 - gi) / 2);

    const char* abase = (const char*)znsw + (size_t)gi * 16384 + l * 16;
    const char* bbase = (const char*)znsw + (size_t)gj * 16384 + l * 16;

    f32x4 acc[4][4];
    #pragma unroll
    for (int mt = 0; mt < 4; ++mt)
        #pragma unroll
        for (int nt = 0; nt < 4; ++nt)
            acc[mt][nt] = (f32x4){0.f, 0.f, 0.f, 0.f};

    pack16 af[2][4], bfr[2][4];
    #pragma unroll
    for (int mt = 0; mt < 4; ++mt) {
        af[0][mt].v  = *(const int4*)(abase + mt * 4096);
        bfr[0][mt].v = *(const int4*)(bbase + mt * 4096);
    }
    #pragma unroll
    for (int kbp = 0; kbp < 4; ++kbp) {     // chunk-pair = K of 64
        const int cur = kbp & 1, nxt = cur ^ 1;
        if (kbp < 3) {
            #pragma unroll
            for (int mt = 0; mt < 4; ++mt) {
                af[nxt][mt].v  = *(const int4*)(abase + mt * 4096 + (kbp + 1) * 1024);
                bfr[nxt][mt].v = *(const int4*)(bbase + mt * 4096 + (kbp + 1) * 1024);
            }
        }
        #pragma unroll
        for (int mt = 0; mt < 4; ++mt)
            #pragma unroll
            for (int nt = 0; nt < 4; ++nt) {
                acc[mt][nt] = __builtin_amdgcn_mfma_f32_16x16x32_fp8_fp8(
                    af[cur][mt].d[0], bfr[cur][nt].d[0], acc[mt][nt], 0, 0, 0);
                acc[mt][nt] = __builtin_amdgcn_mfma_f32_16x16x32_fp8_fp8(
                    af[cur][mt].d[1], bfr[cur][nt].d[1], acc[mt][nt], 0, 0, 0);
            }
    }

    // ---- wave-local epilogue (C/D layout: col = l&15, row = (l>>4)*4+reg) ----
    const int c = l & 15, q = l >> 4;
    const int rsel = c - 4 * q;
    const bool vld = (rsel >= 0) && (rsel < 4);

    if (gi == gj || gj == gi + 64) {
        float dv[4];
        #pragma unroll
        for (int mt = 0; mt < 4; ++mt) {
            float d = acc[mt][mt][0];
            #pragma unroll
            for (int r = 1; r < 4; ++r)
                if (rsel == r) d = acc[mt][mt][r];
            dv[mt] = d;
        }
        if (vld) {
            float* dst = (gi == gj) ? selfdot : pairdot;
            #pragma unroll
            for (int mt = 0; mt < 4; ++mt)
                dst[gi * 64 + mt * 16 + c] = dv[mt];
        }
    }

    #pragma unroll
    for (int mt = 0; mt < 4; ++mt)
        #pragma unroll
        for (int nt = 0; nt < 4; ++nt)
            #pragma unroll
            for (int r = 0; r < 4; ++r)
                acc[mt][nt][r] = __expf(acc[mt][nt][r] * INV_TAU);

    // row sums -> P[gj][gi*64 + ...]
    float rs[4][4];
    #pragma unroll
    for (int mt = 0; mt < 4; ++mt)
        #pragma unroll
        for (int r = 0; r < 4; ++r)
            rs[mt][r] = acc[mt][0][r] + acc[mt][1][r] + acc[mt][2][r] + acc[mt][3][r];
    #pragma unroll
    for (int off = 1; off <= 8; off <<= 1)
        #pragma unroll
        for (int mt = 0; mt < 4; ++mt)
            #pragma unroll
            for (int r = 0; r < 4; ++r)
                rs[mt][r] += __shfl_xor(rs[mt][r], off);
    if (c == 0) {
        #pragma unroll
        for (int mt = 0; mt < 4; ++mt) {
            const f32x4 o4 = (f32x4){rs[mt][0], rs[mt][1], rs[mt][2], rs[mt][3]};
            __builtin_nontemporal_store(o4,
                (f32x4*)&P[(size_t)gj * N_ROWS + gi * 64 + mt * 16 + q * 4]);
        }
    }

    // col sums (strictly-upper) -> P[gi][gj*64 + ...]
    if (gi != gj) {
        float cs[4];
        #pragma unroll
        for (int nt = 0; nt < 4; ++nt) {
            float s = 0.f;
            #pragma unroll
            for (int mt = 0; mt < 4; ++mt)
                #pragma unroll
                for (int r = 0; r < 4; ++r)
                    s += acc[mt][nt][r];
            s += __shfl_xor(s, 16);
            s += __shfl_xor(s, 32);
            cs[nt] = s;
        }
        if (q == 0) {
            #pragma unroll
            for (int nt = 0; nt < 4; ++nt)
                __builtin_nontemporal_store(cs[nt],
                    &P[(size_t)gi * N_ROWS + gj * 64 + nt * 16 + c]);
        }
    }
}

// ---------------- Kernel 3: per-row loss, atomic mean -----------------------
__global__ __launch_bounds__(256) void kfinal(const float* __restrict__ P,
                                              const float* __restrict__ selfdot,
                                              const float* __restrict__ pairdot,
                                              float* __restrict__ out) {
    const int i = blockIdx.x * 256 + threadIdx.x;
    float s = 0.f;
    #pragma unroll
    for (int st = 0; st < NG; ++st)
        s += P[(size_t)st * N_ROWS + i];
    const float selfe = __expf(selfdot[i] * INV_TAU);
    const float pd    = pairdot[(i < BSZ) ? i : i - BSZ];
    float loss = logf(s - selfe + EPS_REF) - pd * INV_TAU;
    #pragma unroll
    for (int off = 32; off >= 1; off >>= 1) loss += __shfl_xor(loss, off);
    __shared__ float wsum[4];
    if ((threadIdx.x & 63) == 0) wsum[threadIdx.x >> 6] = loss;
    __syncthreads();
    if (threadIdx.x == 0)
        atomicAdd(out, (wsum[0] + wsum[1] + wsum[2] + wsum[3]) * (1.0f / (float)N_ROWS));
}

extern "C" void kernel_launch(void* const* d_in, const int* in_sizes, int n_in,
                              void* d_out, int out_size, void* d_ws, size_t ws_size,
                              hipStream_t stream) {
    const float* zi = (const float*)d_in[0];
    const float* zj = (const float*)d_in[1];
    float* out = (float*)d_out;

    char* ws = (char*)d_ws;
    unsigned char* znsw = (unsigned char*)ws;                       // 2 MB
    float* P       = (float*)(ws + 2 * 1024 * 1024);                // 4 MB
    float* selfdot = (float*)(ws + 6 * 1024 * 1024);                // 32 KB
    float* pairdot = (float*)(ws + 6 * 1024 * 1024 + 32 * 1024);    // 16 KB

    (void)hipMemsetAsync(out, 0, sizeof(float), stream);
    knorm <<<N_ROWS / 16, 256, 0, stream>>>(zi, zj, znsw);
    kgemm <<<NBLK, 256, 0, stream>>>(znsw, P, selfdot, pairdot);
    kfinal<<<N_ROWS / 256, 256, 0, stream>>>(P, selfdot, pairdot, out);
}

// Round 6
// 89.597 us; speedup vs baseline: 1.5150x; 1.5150x over previous
//
#include <hip/hip_runtime.h>
#include <hip/hip_bf16.h>

// NT-Xent loss, BS=4096, D=256, TAU=0.5.
// R6 = R5 + kfinal v2. R5's kfinal was a serial dependent-load chain
// (VGPR=8, 1 outstanding 4B load x 128 strips x ~900cyc, 0.5 waves/CU ->
// 52 us). v2: 128 blocks x 4 waves, 32 independent coalesced loads/thread,
// LDS combine -> latency hidden by ILP+TLP.
//
// znsw layout (fragment-native for mfma_f32_16x16x32_fp8_fp8):
//   16-row group rg, chunk-pair kbp (0..3): 64 lanes x 16B at
//   byte ((rg*4+kbp)*64 + fl)*16. Lane fl: row = rg*16 + (fl&15),
//   low 8B  = k = (2*kbp+0)*32 + (fl>>4)*8 + j  (j=0..7),
//   high 8B = k = (2*kbp+1)*32 + (fl>>4)*8 + j.

#define N_ROWS 8192
#define BSZ    4096
#define DIM    256
#define INV_TAU 2.0f
#define EPS_REF 1e-8f
#define COS_EPS 1e-8f
#define NG      128                    // 64-row groups
#define NTT     (NG * (NG + 1) / 2)    // 8256 triangular wave-tiles
#define NBLK    (NTT / 4)              // 2064 blocks of 4 waves

typedef __attribute__((ext_vector_type(4))) float f32x4;
typedef long long i64;
typedef union { int4 v; i64 d[2]; } pack16;

// ---------------- Kernel 1: normalize + fp8 quantize + fragment swizzle -----
__global__ __launch_bounds__(256) void knorm(const float* __restrict__ zi,
                                             const float* __restrict__ zj,
                                             unsigned char* __restrict__ znsw) {
    __shared__ float lds[4096];    // 16 rows x 256
    __shared__ float nrm[16];
    const int rg = blockIdx.x;     // 0..511
    const int t  = threadIdx.x;
    const int row0 = rg * 16;

    #pragma unroll
    for (int s = 0; s < 4; ++s) {
        const int e = s * 1024 + t * 4;          // element in 16x256 panel
        const int r = row0 + (e >> 8);
        const int k = e & 255;
        const float* src = (r < BSZ) ? zi + (size_t)r * DIM + k
                                     : zj + (size_t)(r - BSZ) * DIM + k;
        *(float4*)&lds[e] = *(const float4*)src;
    }
    __syncthreads();

    {   // norms: 16 threads per row, 16 elems each, xor-reduce
        const int r = t >> 4, p = t & 15;
        float ss = 0.f;
        #pragma unroll
        for (int j = 0; j < 16; ++j) { const float x = lds[r * 256 + p * 16 + j]; ss += x * x; }
        ss += __shfl_xor(ss, 1); ss += __shfl_xor(ss, 2);
        ss += __shfl_xor(ss, 4); ss += __shfl_xor(ss, 8);
        if (p == 0) nrm[r] = 1.0f / fmaxf(sqrtf(ss), COS_EPS);
    }
    __syncthreads();

    // emit one 16B fragment word per thread (block writes 4KB contiguous)
    const int kbp = t >> 6, fl = t & 63;
    const int r16 = fl & 15, q = fl >> 4;
    const float inv = nrm[r16];
    int w[4];
    #pragma unroll
    for (int h = 0; h < 2; ++h) {
        const int kk = (2 * kbp + h) * 32 + q * 8;
        float f[8];
        #pragma unroll
        for (int j = 0; j < 8; ++j) f[j] = lds[r16 * 256 + kk + j] * inv;
        int a = 0, b = 0;
        a = __builtin_amdgcn_cvt_pk_fp8_f32(f[0], f[1], a, false);
        a = __builtin_amdgcn_cvt_pk_fp8_f32(f[2], f[3], a, true);
        b = __builtin_amdgcn_cvt_pk_fp8_f32(f[4], f[5], b, false);
        b = __builtin_amdgcn_cvt_pk_fp8_f32(f[6], f[7], b, true);
        w[h * 2] = a; w[h * 2 + 1] = b;
    }
    *(int4*)(znsw + ((size_t)(rg * 4 + kbp) * 64 + fl) * 16) = make_int4(w[0], w[1], w[2], w[3]);
}

// ---------------- Kernel 2: triangular Gram, direct-load fp8 MFMA -----------
__global__ __launch_bounds__(256, 2) void kgemm(const unsigned char* __restrict__ znsw,
                                                float* __restrict__ P,
                                                float* __restrict__ selfdot,
                                                float* __restrict__ pairdot) {
    const int w = threadIdx.x >> 6;
    const int l = threadIdx.x & 63;
    const int t = blockIdx.x * 4 + w;

    // triangular decode: S(g) = g*(257-g)/2 <= t < S(g+1)
    int gi = (int)((257.0f - sqrtf(66049.0f - 8.0f * (float)t)) * 0.5f);
    while ((gi + 1) * (257 - (gi + 1)) / 2 <= t) ++gi;
    while (gi * (257 - gi) / 2 > t) --gi;
    const int gj = gi + (t - gi * (257 - gi) / 2);

    const char* abase = (const char*)znsw + (size_t)gi * 16384 + l * 16;
    const char* bbase = (const char*)znsw + (size_t)gj * 16384 + l * 16;

    f32x4 acc[4][4];
    #pragma unroll
    for (int mt = 0; mt < 4; ++mt)
        #pragma unroll
        for (int nt = 0; nt < 4; ++nt)
            acc[mt][nt] = (f32x4){0.f, 0.f, 0.f, 0.f};

    pack16 af[2][4], bfr[2][4];
    #pragma unroll
    for (int mt = 0; mt < 4; ++mt) {
        af[0][mt].v  = *(const int4*)(abase + mt * 4096);
        bfr[0][mt].v = *(const int4*)(bbase + mt * 4096);
    }
    #pragma unroll
    for (int kbp = 0; kbp < 4; ++kbp) {     // chunk-pair = K of 64
        const int cur = kbp & 1, nxt = cur ^ 1;
        if (kbp < 3) {
            #pragma unroll
            for (int mt = 0; mt < 4; ++mt) {
                af[nxt][mt].v  = *(const int4*)(abase + mt * 4096 + (kbp + 1) * 1024);
                bfr[nxt][mt].v = *(const int4*)(bbase + mt * 4096 + (kbp + 1) * 1024);
            }
        }
        #pragma unroll
        for (int mt = 0; mt < 4; ++mt)
            #pragma unroll
            for (int nt = 0; nt < 4; ++nt) {
                acc[mt][nt] = __builtin_amdgcn_mfma_f32_16x16x32_fp8_fp8(
                    af[cur][mt].d[0], bfr[cur][nt].d[0], acc[mt][nt], 0, 0, 0);
                acc[mt][nt] = __builtin_amdgcn_mfma_f32_16x16x32_fp8_fp8(
                    af[cur][mt].d[1], bfr[cur][nt].d[1], acc[mt][nt], 0, 0, 0);
            }
    }

    // ---- wave-local epilogue (C/D layout: col = l&15, row = (l>>4)*4+reg) ----
    const int c = l & 15, q = l >> 4;
    const int rsel = c - 4 * q;
    const bool vld = (rsel >= 0) && (rsel < 4);

    if (gi == gj || gj == gi + 64) {
        float dv[4];
        #pragma unroll
        for (int mt = 0; mt < 4; ++mt) {
            float d = acc[mt][mt][0];
            #pragma unroll
            for (int r = 1; r < 4; ++r)
                if (rsel == r) d = acc[mt][mt][r];
            dv[mt] = d;
        }
        if (vld) {
            float* dst = (gi == gj) ? selfdot : pairdot;
            #pragma unroll
            for (int mt = 0; mt < 4; ++mt)
                dst[gi * 64 + mt * 16 + c] = dv[mt];
        }
    }

    #pragma unroll
    for (int mt = 0; mt < 4; ++mt)
        #pragma unroll
        for (int nt = 0; nt < 4; ++nt)
            #pragma unroll
            for (int r = 0; r < 4; ++r)
                acc[mt][nt][r] = __expf(acc[mt][nt][r] * INV_TAU);

    // row sums -> P[gj][gi*64 + ...]
    float rs[4][4];
    #pragma unroll
    for (int mt = 0; mt < 4; ++mt)
        #pragma unroll
        for (int r = 0; r < 4; ++r)
            rs[mt][r] = acc[mt][0][r] + acc[mt][1][r] + acc[mt][2][r] + acc[mt][3][r];
    #pragma unroll
    for (int off = 1; off <= 8; off <<= 1)
        #pragma unroll
        for (int mt = 0; mt < 4; ++mt)
            #pragma unroll
            for (int r = 0; r < 4; ++r)
                rs[mt][r] += __shfl_xor(rs[mt][r], off);
    if (c == 0) {
        #pragma unroll
        for (int mt = 0; mt < 4; ++mt) {
            const f32x4 o4 = (f32x4){rs[mt][0], rs[mt][1], rs[mt][2], rs[mt][3]};
            __builtin_nontemporal_store(o4,
                (f32x4*)&P[(size_t)gj * N_ROWS + gi * 64 + mt * 16 + q * 4]);
        }
    }

    // col sums (strictly-upper) -> P[gi][gj*64 + ...]
    if (gi != gj) {
        float cs[4];
        #pragma unroll
        for (int nt = 0; nt < 4; ++nt) {
            float s = 0.f;
            #pragma unroll
            for (int mt = 0; mt < 4; ++mt)
                #pragma unroll
                for (int r = 0; r < 4; ++r)
                    s += acc[mt][nt][r];
            s += __shfl_xor(s, 16);
            s += __shfl_xor(s, 32);
            cs[nt] = s;
        }
        if (q == 0) {
            #pragma unroll
            for (int nt = 0; nt < 4; ++nt)
                __builtin_nontemporal_store(cs[nt],
                    &P[(size_t)gi * N_ROWS + gj * 64 + nt * 16 + c]);
        }
    }
}

// ---------------- Kernel 3: per-row loss (latency-hiding version) -----------
// 128 blocks x 256 thr. Block owns 64 rows; wave w sums strips w*32..w*32+31
// (32 independent coalesced loads per thread), LDS combine, wave 0 finishes.
__global__ __launch_bounds__(256) void kfinal(const float* __restrict__ P,
                                              const float* __restrict__ selfdot,
                                              const float* __restrict__ pairdot,
                                              float* __restrict__ out) {
    const int l = threadIdx.x & 63;        // row within block
    const int w = threadIdx.x >> 6;        // strip quarter
    const int row = blockIdx.x * 64 + l;
    float s = 0.f;
    #pragma unroll
    for (int st = 0; st < 32; ++st)
        s += P[(size_t)(w * 32 + st) * N_ROWS + row];
    __shared__ float wsum[4][64];
    wsum[w][l] = s;
    __syncthreads();
    if (w == 0) {
        const float tot = wsum[0][l] + wsum[1][l] + wsum[2][l] + wsum[3][l];
        const float selfe = __expf(selfdot[row] * INV_TAU);
        const float pd    = pairdot[(row < BSZ) ? row : row - BSZ];
        float loss = logf(tot - selfe + EPS_REF) - pd * INV_TAU;
        #pragma unroll
        for (int off = 32; off >= 1; off >>= 1) loss += __shfl_xor(loss, off);
        if (l == 0) atomicAdd(out, loss * (1.0f / (float)N_ROWS));
    }
}

extern "C" void kernel_launch(void* const* d_in, const int* in_sizes, int n_in,
                              void* d_out, int out_size, void* d_ws, size_t ws_size,
                              hipStream_t stream) {
    const float* zi = (const float*)d_in[0];
    const float* zj = (const float*)d_in[1];
    float* out = (float*)d_out;

    char* ws = (char*)d_ws;
    unsigned char* znsw = (unsigned char*)ws;                       // 2 MB
    float* P       = (float*)(ws + 2 * 1024 * 1024);                // 4 MB
    float* selfdot = (float*)(ws + 6 * 1024 * 1024);                // 32 KB
    float* pairdot = (float*)(ws + 6 * 1024 * 1024 + 32 * 1024);    // 16 KB

    (void)hipMemsetAsync(out, 0, sizeof(float), stream);
    knorm <<<N_ROWS / 16, 256, 0, stream>>>(zi, zj, znsw);
    kgemm <<<NBLK, 256, 0, stream>>>(znsw, P, selfdot, pairdot);
    kfinal<<<N_ROWS / 64, 256, 0, stream>>>(P, selfdot, pairdot, out);
}

// Round 7
// 89.432 us; speedup vs baseline: 1.5177x; 1.0018x over previous
//
#include <hip/hip_runtime.h>
#include <hip/hip_bf16.h>

// NT-Xent loss, BS=4096, D=256, TAU=0.5.
// R7: kgemm restructured. Block = 128x128 triangular super-tile; both
// 128-row fp8 panels (all K=256) staged to LDS once via global_load_lds
// width-16 (deep async queue), ONE barrier, then 4 waves (64x64 quadrants)
// run 128 MFMAs each straight from LDS (contiguous 16B/lane ds_read_b128,
// conflict-free). Panel sharing halves global reads vs R6 (264->133 MB).
// out=0 folded into knorm (one fewer graph node).
//
// znsw layout (fragment-native for mfma_f32_16x16x32_fp8_fp8):
//   16-row group rg, chunk-pair kbp (0..3): 64 lanes x 16B at
//   byte ((rg*4+kbp)*64 + fl)*16. Lane fl: row = rg*16 + (fl&15),
//   low 8B  = k = (2*kbp+0)*32 + (fl>>4)*8 + j  (j=0..7),
//   high 8B = k = (2*kbp+1)*32 + (fl>>4)*8 + j.
// A 128-row panel (8 rgs) is 32KB contiguous -> LDS copy is 1:1.

#define N_ROWS 8192
#define BSZ    4096
#define DIM    256
#define INV_TAU 2.0f
#define EPS_REF 1e-8f
#define COS_EPS 1e-8f
#define NG2     64                     // 128-row groups
#define NBLK2   (NG2 * (NG2 + 1) / 2)  // 2080 triangular blocks

typedef __attribute__((ext_vector_type(4))) float f32x4;
typedef long long i64;
typedef union { int4 v; i64 d[2]; } pack16;

// ---------------- Kernel 1: normalize + fp8 quantize + fragment swizzle -----
__global__ __launch_bounds__(256) void knorm(const float* __restrict__ zi,
                                             const float* __restrict__ zj,
                                             unsigned char* __restrict__ znsw,
                                             float* __restrict__ out) {
    __shared__ float lds[4096];    // 16 rows x 256
    __shared__ float nrm[16];
    const int rg = blockIdx.x;     // 0..511
    const int t  = threadIdx.x;
    const int row0 = rg * 16;
    if (rg == 0 && t == 0) out[0] = 0.f;    // kfinal atomics run after us

    #pragma unroll
    for (int s = 0; s < 4; ++s) {
        const int e = s * 1024 + t * 4;          // element in 16x256 panel
        const int r = row0 + (e >> 8);
        const int k = e & 255;
        const float* src = (r < BSZ) ? zi + (size_t)r * DIM + k
                                     : zj + (size_t)(r - BSZ) * DIM + k;
        *(float4*)&lds[e] = *(const float4*)src;
    }
    __syncthreads();

    {   // norms: 16 threads per row, 16 elems each, xor-reduce
        const int r = t >> 4, p = t & 15;
        float ss = 0.f;
        #pragma unroll
        for (int j = 0; j < 16; ++j) { const float x = lds[r * 256 + p * 16 + j]; ss += x * x; }
        ss += __shfl_xor(ss, 1); ss += __shfl_xor(ss, 2);
        ss += __shfl_xor(ss, 4); ss += __shfl_xor(ss, 8);
        if (p == 0) nrm[r] = 1.0f / fmaxf(sqrtf(ss), COS_EPS);
    }
    __syncthreads();

    // emit one 16B fragment word per thread (block writes 4KB contiguous)
    const int kbp = t >> 6, fl = t & 63;
    const int r16 = fl & 15, q = fl >> 4;
    const float inv = nrm[r16];
    int w[4];
    #pragma unroll
    for (int h = 0; h < 2; ++h) {
        const int kk = (2 * kbp + h) * 32 + q * 8;
        float f[8];
        #pragma unroll
        for (int j = 0; j < 8; ++j) f[j] = lds[r16 * 256 + kk + j] * inv;
        int a = 0, b = 0;
        a = __builtin_amdgcn_cvt_pk_fp8_f32(f[0], f[1], a, false);
        a = __builtin_amdgcn_cvt_pk_fp8_f32(f[2], f[3], a, true);
        b = __builtin_amdgcn_cvt_pk_fp8_f32(f[4], f[5], b, false);
        b = __builtin_amdgcn_cvt_pk_fp8_f32(f[6], f[7], b, true);
        w[h * 2] = a; w[h * 2 + 1] = b;
    }
    *(int4*)(znsw + ((size_t)(rg * 4 + kbp) * 64 + fl) * 16) = make_int4(w[0], w[1], w[2], w[3]);
}

// ---------------- Kernel 2: triangular Gram, LDS-staged fp8 MFMA ------------
__global__ __launch_bounds__(256, 2) void kgemm(const unsigned char* __restrict__ znsw,
                                                float* __restrict__ P,
                                                float* __restrict__ selfdot,
                                                float* __restrict__ pairdot) {
    __shared__ __align__(16) unsigned char pan[2][32768];
    const int w = threadIdx.x >> 6;
    const int l = threadIdx.x & 63;

    // triangular decode over NG2=64: S(G) = G*(129-G)/2
    const int t = blockIdx.x;
    int Gi = (int)((129.0f - sqrtf(16641.0f - 8.0f * (float)t)) * 0.5f);
    while ((Gi + 1) * (129 - (Gi + 1)) / 2 <= t) ++Gi;
    while (Gi * (129 - Gi) / 2 > t) --Gi;
    const int Gj = Gi + (t - Gi * (129 - Gi) / 2);

    // stage both 32KB panels (all of K) -- 1:1 contiguous copy
    const char* srcA = (const char*)znsw + (size_t)Gi * 32768;
    const char* srcB = (const char*)znsw + (size_t)Gj * 32768;
    #pragma unroll
    for (int sub = 0; sub < 8; ++sub) {
        const int off = sub * 4096 + w * 1024;
        __builtin_amdgcn_global_load_lds(
            (const __attribute__((address_space(1))) void*)(srcA + off + l * 16),
            (__attribute__((address_space(3))) void*)(&pan[0][off]), 16, 0, 0);
        __builtin_amdgcn_global_load_lds(
            (const __attribute__((address_space(1))) void*)(srcB + off + l * 16),
            (__attribute__((address_space(3))) void*)(&pan[1][off]), 16, 0, 0);
    }
    __syncthreads();

    // quadrant: rows (w>>1)*64, cols (w&1)*64
    const int rh = w >> 1, ch = w & 1;
    const char* Ap = (const char*)&pan[0][0] + rh * 16384 + l * 16;
    const char* Bp = (const char*)&pan[1][0] + ch * 16384 + l * 16;

    f32x4 acc[4][4];
    #pragma unroll
    for (int mt = 0; mt < 4; ++mt)
        #pragma unroll
        for (int nt = 0; nt < 4; ++nt)
            acc[mt][nt] = (f32x4){0.f, 0.f, 0.f, 0.f};

    #pragma unroll
    for (int kbp = 0; kbp < 4; ++kbp) {
        pack16 a4[4], b4[4];
        #pragma unroll
        for (int mt = 0; mt < 4; ++mt) a4[mt].v = *(const int4*)(Ap + (mt * 4 + kbp) * 1024);
        #pragma unroll
        for (int nt = 0; nt < 4; ++nt) b4[nt].v = *(const int4*)(Bp + (nt * 4 + kbp) * 1024);
        #pragma unroll
        for (int mt = 0; mt < 4; ++mt)
            #pragma unroll
            for (int nt = 0; nt < 4; ++nt) {
                acc[mt][nt] = __builtin_amdgcn_mfma_f32_16x16x32_fp8_fp8(
                    a4[mt].d[0], b4[nt].d[0], acc[mt][nt], 0, 0, 0);
                acc[mt][nt] = __builtin_amdgcn_mfma_f32_16x16x32_fp8_fp8(
                    a4[mt].d[1], b4[nt].d[1], acc[mt][nt], 0, 0, 0);
            }
    }

    // ---- wave-local epilogue (C/D layout: col = l&15, row = (l>>4)*4+reg) ----
    const int c = l & 15, q = l >> 4;
    const int rsel = c - 4 * q;
    const bool vld = (rsel >= 0) && (rsel < 4);

    // self/pair diagonals live in quadrants with rh==ch (w==0, w==3)
    if ((Gi == Gj || Gj == Gi + 32) && rh == ch) {
        float dv[4];
        #pragma unroll
        for (int mt = 0; mt < 4; ++mt) {
            float d = acc[mt][mt][0];
            #pragma unroll
            for (int r = 1; r < 4; ++r)
                if (rsel == r) d = acc[mt][mt][r];
            dv[mt] = d;
        }
        if (vld) {
            float* dst = (Gi == Gj) ? selfdot : pairdot;
            #pragma unroll
            for (int mt = 0; mt < 4; ++mt)
                dst[Gi * 128 + rh * 64 + mt * 16 + c] = dv[mt];
        }
    }

    #pragma unroll
    for (int mt = 0; mt < 4; ++mt)
        #pragma unroll
        for (int nt = 0; nt < 4; ++nt)
            #pragma unroll
            for (int r = 0; r < 4; ++r)
                acc[mt][nt][r] = __expf(acc[mt][nt][r] * INV_TAU);

    // row sums -> P[Gj*2+ch][Gi*128 + rh*64 + ...]
    float rs[4][4];
    #pragma unroll
    for (int mt = 0; mt < 4; ++mt)
        #pragma unroll
        for (int r = 0; r < 4; ++r)
            rs[mt][r] = acc[mt][0][r] + acc[mt][1][r] + acc[mt][2][r] + acc[mt][3][r];
    #pragma unroll
    for (int off = 1; off <= 8; off <<= 1)
        #pragma unroll
        for (int mt = 0; mt < 4; ++mt)
            #pragma unroll
            for (int r = 0; r < 4; ++r)
                rs[mt][r] += __shfl_xor(rs[mt][r], off);
    if (c == 0) {
        #pragma unroll
        for (int mt = 0; mt < 4; ++mt) {
            const f32x4 o4 = (f32x4){rs[mt][0], rs[mt][1], rs[mt][2], rs[mt][3]};
            __builtin_nontemporal_store(o4,
                (f32x4*)&P[(size_t)(Gj * 2 + ch) * N_ROWS + Gi * 128 + rh * 64 + mt * 16 + q * 4]);
        }
    }

    // col sums (strictly-upper blocks) -> P[Gi*2+rh][Gj*128 + ch*64 + ...]
    if (Gi != Gj) {
        float cs[4];
        #pragma unroll
        for (int nt = 0; nt < 4; ++nt) {
            float s = 0.f;
            #pragma unroll
            for (int mt = 0; mt < 4; ++mt)
                #pragma unroll
                for (int r = 0; r < 4; ++r)
                    s += acc[mt][nt][r];
            s += __shfl_xor(s, 16);
            s += __shfl_xor(s, 32);
            cs[nt] = s;
        }
        if (q == 0) {
            #pragma unroll
            for (int nt = 0; nt < 4; ++nt)
                __builtin_nontemporal_store(cs[nt],
                    &P[(size_t)(Gi * 2 + rh) * N_ROWS + Gj * 128 + ch * 64 + nt * 16 + c]);
        }
    }
}

// ---------------- Kernel 3: per-row loss (latency-hiding) -------------------
// 128 blocks x 256 thr. Block owns 64 rows; wave w sums strips w*32..w*32+31
// (32 independent coalesced loads per thread), LDS combine, wave 0 finishes.
__global__ __launch_bounds__(256) void kfinal(const float* __restrict__ P,
                                              const float* __restrict__ selfdot,
                                              const float* __restrict__ pairdot,
                                              float* __restrict__ out) {
    const int l = threadIdx.x & 63;        // row within block
    const int w = threadIdx.x >> 6;        // strip quarter
    const int row = blockIdx.x * 64 + l;
    float s = 0.f;
    #pragma unroll
    for (int st = 0; st < 32; ++st)
        s += P[(size_t)(w * 32 + st) * N_ROWS + row];
    __shared__ float wsum[4][64];
    wsum[w][l] = s;
    __syncthreads();
    if (w == 0) {
        const float tot = wsum[0][l] + wsum[1][l] + wsum[2][l] + wsum[3][l];
        const float selfe = __expf(selfdot[row] * INV_TAU);
        const float pd    = pairdot[(row < BSZ) ? row : row - BSZ];
        float loss = logf(tot - selfe + EPS_REF) - pd * INV_TAU;
        #pragma unroll
        for (int off = 32; off >= 1; off >>= 1) loss += __shfl_xor(loss, off);
        if (l == 0) atomicAdd(out, loss * (1.0f / (float)N_ROWS));
    }
}

extern "C" void kernel_launch(void* const* d_in, const int* in_sizes, int n_in,
                              void* d_out, int out_size, void* d_ws, size_t ws_size,
                              hipStream_t stream) {
    const float* zi = (const float*)d_in[0];
    const float* zj = (const float*)d_in[1];
    float* out = (float*)d_out;

    char* ws = (char*)d_ws;
    unsigned char* znsw = (unsigned char*)ws;                       // 2 MB
    float* P       = (float*)(ws + 2 * 1024 * 1024);                // 4 MB
    float* selfdot = (float*)(ws + 6 * 1024 * 1024);                // 32 KB
    float* pairdot = (float*)(ws + 6 * 1024 * 1024 + 32 * 1024);    // 16 KB

    knorm <<<N_ROWS / 16, 256, 0, stream>>>(zi, zj, znsw, out);
    kgemm <<<NBLK2, 256, 0, stream>>>(znsw, P, selfdot, pairdot);
    kfinal<<<N_ROWS / 64, 256, 0, stream>>>(P, selfdot, pairdot, out);
}